// Round 12
// baseline (156.610 us; speedup 1.0000x reference)
//
#include <hip/hip_runtime.h>
#include <hip/hip_bf16.h>
#include <stdint.h>

typedef __attribute__((ext_vector_type(4)))  float  floatx4;
typedef __attribute__((ext_vector_type(8)))  short  short8;
typedef __attribute__((ext_vector_type(8)))  unsigned short ushortx8;
typedef __attribute__((ext_vector_type(4)))  unsigned short ushortx4;

#define B_  2
#define T_  2048
#define E_  1024
#define H_  16
#define D_  64
#define C_  128
#define NC_ 16
#define M_  4096   /* B*T */
#define EPS_ 1e-5f

__device__ __forceinline__ unsigned short f2b(float f) {
    union { float f; unsigned int u; } v; v.f = f;
    unsigned int r = v.u + 0x7fffu + ((v.u >> 16) & 1u);
    return (unsigned short)(r >> 16);
}
__device__ __forceinline__ float b2f(unsigned short b) {
    union { unsigned int u; float f; } v; v.u = ((unsigned int)b) << 16;
    return v.f;
}

// Swizzled fragment staging (R3/R4; R7/R9/R10/R13 errata):
//   staging tile = 16 rows x 32 k (1 KB). lane i fetches global (row = i>>2,
//   kseg = (i&3) ^ ((i>>3)&3)) -> LDS slot i (16B). Fragment read: lane l
//   reads slot sigma(l&15, l>>4) with a WAVE-UNIFORM tile base (R7 errata).
//   R9: sigma-staged GEMM fragments MUST come from LDS. R10: no blockIdx swizzle.
//   R15: tile growth alone is not the lever. R16: dbuf+syncthreads = only -10%.
//   R17: counted vmcnt + raw s_barrier; wall 161.5. R18: separate prefix
//   kernel = net loss. R19: device-scope fences in hot path = disaster.
//   R20: 192-wide @ 4 waves/1 blk/CU = collapse (occupancy). R21: wall
//   accounting non-additive (async fill). R22: qkv 256x192 @ 512thr/8waves/
//   1 blk/CU -> 157.0 (validated). R23: triangle balancing FLAT -> attn is
//   traffic-bound, not MFMA-bound. R24: bf16 pre-transposed chunk states ->
//   153.5 (validated, absmax unchanged).
//   R25 (RESUBMIT — R11 bench was GPUAcquisitionTimeout, no data): qkv
//   K-loop 2-phase -> 4-phase (kh x mi-half): each phase {7 ds_read ->
//   barrier -> setprio(1) 12 MFMA setprio(0) -> barrier}, stageB inside
//   phase 2, step-top stageA+vmcnt(4) unchanged. Phase-split creates wave
//   role-diversity (T5 enablement per m218b; 8ph/2ph=1.10x m248v2).
//   Addressing and buffer lifetimes identical to R22.
__device__ __forceinline__ int stage_seg(int i) { return (i & 3) ^ ((i >> 3) & 3); }
__device__ __forceinline__ int frag_slot(int lane) {
    int m = lane & 15, q = lane >> 4;
    return m * 4 + (q ^ ((m >> 1) & 3));
}

// ---------------- fused fp32 -> bf16 convert: x | Wq | Wk | Wv | Wo ----------------
__global__ __launch_bounds__(256) void convert_all(const float* __restrict__ x,
                                                   const float* __restrict__ Wq,
                                                   const float* __restrict__ Wk,
                                                   const float* __restrict__ Wv,
                                                   const float* __restrict__ Wo,
                                                   unsigned short* __restrict__ dst) {
    int i = (blockIdx.x * 256 + threadIdx.x) * 4;
    const float* s; int off;
    if (i < M_ * E_) { s = x; off = i; }
    else {
        int j = i - M_ * E_;
        int which = j >> 20;
        s = (which == 0) ? Wq : (which == 1) ? Wk : (which == 2) ? Wv : Wo;
        off = j & ((1 << 20) - 1);
    }
    float4 f = *(const float4*)(s + off);
    ushortx4 o;
    o[0] = f2b(f.x); o[1] = f2b(f.y); o[2] = f2b(f.z); o[3] = f2b(f.w);
    *(ushortx4*)(dst + i) = o;
}

// ---------------- QKV projection GEMM: C[4096,3072] = X @ W^T, phi on q,k ----------------
// R22 geometry (256x192, BK=64, 512 thr / 8 waves 2x4, dbuf 112 KB, grid
// 16x16 = 256 = 1 blk/CU) + R25 4-phase K-step schedule.
__global__ __launch_bounds__(512) void gemm_qkv(const unsigned short* __restrict__ A,
                                                const unsigned short* __restrict__ Bm,
                                                unsigned short* __restrict__ Cb) {
    const int N = 3 * E_, K = E_;
    __shared__ __align__(16) unsigned short smem[57344];   // 112 KB
    unsigned short* at0 = smem;                            // 32 tiles (32 KB)
    unsigned short* bt0 = smem + 16384;                    // 24 tiles (24 KB)
    unsigned short* at1 = smem + 28672;
    unsigned short* bt1 = smem + 45056;
    int tid = threadIdx.x;
    int wave = tid >> 6, lane = tid & 63;
    int wr = wave >> 2, wc = wave & 3;                     // 2 x 4 wave grid
    int m = lane & 15, q = lane >> 4;
    int srow = lane >> 2, sseg = stage_seg(lane);
    int fs = frag_slot(lane);
    int row0 = blockIdx.y * 256, col0 = blockIdx.x * 192;
    floatx4 acc[8][3];
    for (int i = 0; i < 8; i++) for (int j = 0; j < 3; j++) acc[i][j] = floatx4{0.f, 0.f, 0.f, 0.f};

    auto stageA = [&](unsigned short* at, int k0) {      // 4 loads/wave: 32 A tiles
        for (int p = 0; p < 4; p++) {
            int t = p * 8 + wave;                        // rb = t&15, kh = t>>4
            const unsigned short* ga = A + (size_t)(row0 + (t & 15) * 16 + srow) * K + k0 + (t >> 4) * 32 + sseg * 8;
            __builtin_amdgcn_global_load_lds((const __attribute__((address_space(1))) unsigned int*)ga,
                (__attribute__((address_space(3))) unsigned int*)(at + t * 512), 16, 0, 0);
        }
    };
    auto stageB = [&](unsigned short* bt, int k0) {      // 3 loads/wave: 24 B tiles
        for (int p = 0; p < 3; p++) {
            int u = p * 8 + wave;                        // rb = u%12, kh = u/12
            int kh = u / 12, rb = u - kh * 12;
            const unsigned short* gb = Bm + (size_t)(col0 + rb * 16 + srow) * K + k0 + kh * 32 + sseg * 8;
            __builtin_amdgcn_global_load_lds((const __attribute__((address_space(1))) unsigned int*)gb,
                (__attribute__((address_space(3))) unsigned int*)(bt + u * 512), 16, 0, 0);
        }
    };
    // R25: 4-phase K-step. Phase ph = (kh<<1)|mh: 7 ds_read (af[4]: rows
    // kh*16+wr*8+mh*4..+3; bf[3]: kh*12+wc*3..+2) -> barrier -> 12 MFMA into
    // acc[mh*4+mi][ni] -> barrier. stageB(next) issued inside phase 2.
    auto kstep4 = [&](const unsigned short* at, const unsigned short* bt,
                      unsigned short* nbt, int nk, bool doStageB) {
#pragma unroll
        for (int ph = 0; ph < 4; ph++) {
            int kh = ph >> 1, mh = ph & 1;
            short8 af[4], bf[3];
            for (int mi = 0; mi < 4; mi++)
                af[mi] = *(const short8*)(at + (kh * 16 + wr * 8 + mh * 4 + mi) * 512 + fs * 8);
            for (int ni = 0; ni < 3; ni++)
                bf[ni] = *(const short8*)(bt + (kh * 12 + wc * 3 + ni) * 512 + fs * 8);
            if (ph == 2 && doStageB) stageB(nbt, nk);
            __builtin_amdgcn_s_barrier();
            __builtin_amdgcn_s_setprio(1);
            for (int mi = 0; mi < 4; mi++)
                for (int ni = 0; ni < 3; ni++)
                    acc[mh * 4 + mi][ni] = __builtin_amdgcn_mfma_f32_16x16x32_bf16(af[mi], bf[ni], acc[mh * 4 + mi][ni], 0, 0, 0);
            __builtin_amdgcn_s_setprio(0);
            __builtin_amdgcn_s_barrier();
        }
    };

    stageA(at0, 0); stageB(bt0, 0);                      // 7 loads in flight
    for (int k0 = 0; k0 < K; k0 += 128) {
        // ---- step A: compute (at0,bt0) @ k0; stage buf1 @ k0+64 ----
        stageA(at1, k0 + 64);                            // outstanding <= 11
        asm volatile("s_waitcnt vmcnt(4)" ::: "memory"); // buf0's 7 retired; next A in flight
        __builtin_amdgcn_s_barrier();
        kstep4(at0, bt0, bt1, k0 + 64, true);
        // ---- step B: compute (at1,bt1) @ k0+64; stage buf0 @ k0+128 ----
        bool more = (k0 + 128 < K);
        if (more) {
            stageA(at0, k0 + 128);
            asm volatile("s_waitcnt vmcnt(4)" ::: "memory");
        } else {
            asm volatile("s_waitcnt vmcnt(0)" ::: "memory");
        }
        __builtin_amdgcn_s_barrier();
        kstep4(at1, bt1, bt0, k0 + 128, more);
    }

    // ---- epilogue: LDS bounce -> coalesced 16B stores ----
    unsigned short* epi = smem + wave * 1792;
    for (int ch = 0; ch < 4; ch++) {
        if (ch) asm volatile("" ::: "memory");
        for (int mi2 = 0; mi2 < 2; mi2++) {
            int mi = ch * 2 + mi2;
            for (int ni = 0; ni < 3; ni++)
                for (int reg = 0; reg < 4; reg++) {
                    int lr = mi2 * 16 + q * 4 + reg;
                    int colw = col0 + wc * 48 + ni * 16 + m;
                    float v = acc[mi][ni][reg];
                    if (colw < 2 * E_) v = (v > 0.f) ? (v + 1.f) : __expf(v);
                    epi[lr * 56 + ni * 16 + m] = f2b(v);
                }
        }
        asm volatile("" ::: "memory");
        for (int slot = 0; slot < 3; slot++) {
            int s = slot * 64 + lane;                    // 192 slots = 32 rows x 6 segs
            int lr = s / 6, seg = s - lr * 6;
            const unsigned short* p = epi + lr * 56 + seg * 8;
            ushortx4 lo = *(const ushortx4*)(p);
            ushortx4 hi = *(const ushortx4*)(p + 4);
            ushortx8 val;
            for (int e = 0; e < 4; e++) { val[e] = lo[e]; val[e + 4] = hi[e]; }
            int row = row0 + wr * 128 + ch * 32 + lr;
            int col = col0 + wc * 48 + seg * 8;
            *(ushortx8*)(Cb + (size_t)row * N + col) = val;
        }
    }
}

// ---------------- Output GEMM: out[4096,1024] = attn @ Wo^T + bo (fp32 out) ----------------
// R17: 128x64 tile, BK=64, dbuf, counted-vmcnt schedule (stage = 4 A + 2 B).
__global__ __launch_bounds__(256) void gemm_out(const unsigned short* __restrict__ A,
                                                const unsigned short* __restrict__ Bm,
                                                const float* __restrict__ bias,
                                                float* __restrict__ Cf) {
    const int N = E_, K = E_;
    __shared__ __align__(16) unsigned short smem[24576];   // 48 KB: 2 x (at 16KB | bt 8KB)
    unsigned short* at0 = smem;
    unsigned short* bt0 = smem + 8192;
    unsigned short* at1 = smem + 12288;
    unsigned short* bt1 = smem + 20480;
    int tid = threadIdx.x;
    int wave = tid >> 6, lane = tid & 63;
    int wr = wave >> 1, wc = wave & 1;
    int m = lane & 15, q = lane >> 4;
    int srow = lane >> 2, sseg = stage_seg(lane);
    int fs = frag_slot(lane);
    int row0 = blockIdx.y * 128, col0 = blockIdx.x * 64;
    floatx4 acc[4][2];
    for (int i = 0; i < 4; i++) for (int j = 0; j < 2; j++) acc[i][j] = floatx4{0.f, 0.f, 0.f, 0.f};

    auto stageA = [&](unsigned short* at, int k0) {
        for (int p = 0; p < 4; p++) {
            int t = p * 4 + wave;
            const unsigned short* ga = A + (size_t)(row0 + (t & 7) * 16 + srow) * K + k0 + (t >> 3) * 32 + sseg * 8;
            __builtin_amdgcn_global_load_lds((const __attribute__((address_space(1))) unsigned int*)ga,
                (__attribute__((address_space(3))) unsigned int*)(at + t * 512), 16, 0, 0);
        }
    };
    auto stageB = [&](unsigned short* bt, int k0) {
        for (int p = 0; p < 2; p++) {
            int u = p * 4 + wave;
            const unsigned short* gb = Bm + (size_t)(col0 + (u & 3) * 16 + srow) * K + k0 + (u >> 2) * 32 + sseg * 8;
            __builtin_amdgcn_global_load_lds((const __attribute__((address_space(1))) unsigned int*)gb,
                (__attribute__((address_space(3))) unsigned int*)(bt + u * 512), 16, 0, 0);
        }
    };
    short8 af[4], bf[2];
    auto frags = [&](const unsigned short* at, const unsigned short* bt, int kh) {
        for (int mi = 0; mi < 4; mi++) af[mi] = *(const short8*)(at + (kh * 8 + wr * 4 + mi) * 512 + fs * 8);
        for (int ci = 0; ci < 2; ci++) bf[ci] = *(const short8*)(bt + (kh * 4 + wc * 2 + ci) * 512 + fs * 8);
    };
    auto mfma8 = [&]() {
        __builtin_amdgcn_s_setprio(1);
        for (int mi = 0; mi < 4; mi++)
            for (int ci = 0; ci < 2; ci++)
                acc[mi][ci] = __builtin_amdgcn_mfma_f32_16x16x32_bf16(af[mi], bf[ci], acc[mi][ci], 0, 0, 0);
        __builtin_amdgcn_s_setprio(0);
    };

    stageA(at0, 0); stageB(bt0, 0);
    for (int k0 = 0; k0 < K; k0 += 128) {
        stageA(at1, k0 + 64);
        asm volatile("s_waitcnt vmcnt(4)" ::: "memory");
        __builtin_amdgcn_s_barrier();
        frags(at0, bt0, 0);
        mfma8();
        frags(at0, bt0, 1);
        stageB(bt1, k0 + 64);
        mfma8();
        __builtin_amdgcn_s_barrier();
        if (k0 + 128 < K) {
            stageA(at0, k0 + 128);
            asm volatile("s_waitcnt vmcnt(4)" ::: "memory");
        } else {
            asm volatile("s_waitcnt vmcnt(0)" ::: "memory");
        }
        __builtin_amdgcn_s_barrier();
        frags(at1, bt1, 0);
        mfma8();
        frags(at1, bt1, 1);
        if (k0 + 128 < K) stageB(bt0, k0 + 128);
        mfma8();
        __builtin_amdgcn_s_barrier();
    }

    int qrow = q * 4;
    for (int ci = 0; ci < 2; ci++) {
        int col = col0 + wc * 32 + ci * 16 + m;
        float bv = bias[col];
        for (int mi = 0; mi < 4; mi++)
            for (int r2 = 0; r2 < 4; r2++) {
                int row = row0 + wr * 64 + mi * 16 + qrow + r2;
                Cf[(size_t)row * N + col] = acc[mi][ci][r2] + bv;
            }
    }
}

// ---------------- per-chunk S_c^T (bf16, [e][d]) and z_c (MFMA) ----------------
// R24: store the chunk state TRANSPOSED in bf16 — exactly the layout attn's
// S_prev panel (ovl, [e][d]) consumes. z_c stays fp32.
__global__ __launch_bounds__(256) void chunk_sums(const unsigned short* __restrict__ qkv,
                                                  unsigned short* __restrict__ Sct,
                                                  float* __restrict__ zc) {
    int c = blockIdx.x, h = blockIdx.y, bb = blockIdx.z;
    __shared__ __align__(16) unsigned short Kt[64 * 132];   // K^T: [d][t], stride 132
    __shared__ __align__(16) unsigned short Vt[80 * 132];   // V^T rows 0..63; row 64 = ones
    int tid = threadIdx.x;
    int lane = tid & 63, w = tid >> 6;
    size_t rowb = (size_t)bb * T_ + (size_t)c * C_;
    int kcol = E_ + h * D_, vcol = 2 * E_ + h * D_;

    {
        int r4 = (tid >> 3) * 4;            // covers 128 rows
        int seg = (tid & 7) * 8;
        ushortx8 kv[4], vv[4];
        for (int t = 0; t < 4; t++) {
            size_t g = (rowb + r4 + t) * 3072;
            kv[t] = *(const ushortx8*)(qkv + g + kcol + seg);
            vv[t] = *(const ushortx8*)(qkv + g + vcol + seg);
        }
        for (int e = 0; e < 8; e++) {
            ushortx4 ka, va;
            for (int t = 0; t < 4; t++) { ka[t] = kv[t][e]; va[t] = vv[t][e]; }
            *(ushortx4*)(Kt + (seg + e) * 132 + r4) = ka;
            *(ushortx4*)(Vt + (seg + e) * 132 + r4) = va;
        }
    }
    if (tid < 128) Vt[64 * 132 + tid] = 0x3f80;  // ones row (bf16 1.0)
    __syncthreads();

    floatx4 acc[5];
    for (int ni = 0; ni < 5; ni++) acc[ni] = floatx4{0.f, 0.f, 0.f, 0.f};
    int lm = lane & 15, lk = (lane >> 4) * 8;
    for (int k0 = 0; k0 < 128; k0 += 32) {
        short8 af = *(const short8*)(Kt + (w * 16 + lm) * 132 + k0 + lk);
        for (int ni = 0; ni < 5; ni++) {
            short8 bf = *(const short8*)(Vt + (ni * 16 + lm) * 132 + k0 + lk);
            acc[ni] = __builtin_amdgcn_mfma_f32_16x16x32_bf16(af, bf, acc[ni], 0, 0, 0);
        }
    }
    // acc[ni][reg] = S[d = r0+reg][e = ni*16+lm]; store transposed bf16:
    // Sct[e*64 + d]. r0 is 4-aligned -> ushortx4 stores.
    size_t base = ((size_t)(bb * H_ + h) * NC_ + c) * (size_t)(D_ * D_);
    int r0 = w * 16 + (lane >> 4) * 4;
    for (int ni = 0; ni < 4; ni++) {
        ushortx4 o;
        for (int reg = 0; reg < 4; reg++) o[reg] = f2b(acc[ni][reg]);
        *(ushortx4*)(Sct + base + (size_t)(ni * 16 + lm) * D_ + r0) = o;
    }
    if (lm == 0) {
        size_t zb = ((size_t)(bb * H_ + h) * NC_ + c) * D_;
        for (int reg = 0; reg < 4; reg++) zc[zb + r0 + reg] = acc[4][reg];
    }
}

// ---------------- per-chunk attention (MFMA) — R23 balanced triangle + R24 bf16 Sct ----------------
// Wave w owns 16-row blocks {w, 7-w}. S_prev summed from bf16 Sct (fp32
// accumulate, vector loads + vector ovl stores). LDS 43.5 KB, 2 barriers.
__global__ __launch_bounds__(256) void attn_kernel(const unsigned short* __restrict__ qkv,
                                                   const unsigned short* __restrict__ Sct,
                                                   const float* __restrict__ zc,
                                                   unsigned short* __restrict__ attn) {
    int c = blockIdx.x, h = blockIdx.y, bb = blockIdx.z;
    __shared__ __align__(16) unsigned short ks[128 * 68];   // K row-major, stride 68
    __shared__ __align__(16) unsigned short vt[64 * 132];   // V^T
    __shared__ __align__(16) unsigned short ovl[128 * 36];  // S_prev^T (stride 68) then P panel (stride 36)
    __shared__ float zsh[64];
    int tid = threadIdx.x;
    int lane = tid & 63, w = tid >> 6;
    int lm = lane & 15, lq = lane >> 4;
    size_t rowb = (size_t)bb * T_ + (size_t)c * C_;
    int qcol = h * D_, kcol = E_ + h * D_, vcol = 2 * E_ + h * D_;
    int rb[2] = { w, 7 - w };                               // this wave's 16-row blocks

    // ---- stage k row-major (vector writes) ----
    for (int s = 0; s < 4; s++) {
        int off = s * 256 + tid;
        int r = off >> 3, seg = (off & 7) * 8;
        ushortx8 k8 = *(const ushortx8*)(qkv + (rowb + r) * 3072 + kcol + seg);
        *(ushortx8*)(ks + r * 68 + seg) = k8;
    }
    // ---- stage v transposed: 4 rows/thread, b64 column writes ----
    {
        int r4 = (tid >> 3) * 4;
        int seg = (tid & 7) * 8;
        ushortx8 vv[4];
        for (int t = 0; t < 4; t++)
            vv[t] = *(const ushortx8*)(qkv + (rowb + r4 + t) * 3072 + vcol + seg);
        for (int e = 0; e < 8; e++) {
            ushortx4 va;
            for (int t = 0; t < 4; t++) va[t] = vv[t][e];
            *(ushortx4*)(vt + (seg + e) * 132 + r4) = va;
        }
    }
    // ---- S_prev = sum_{j<c} Sct[j] (bf16 terms, fp32 accumulate) ----
    // Sct is already [e][d]: thread owns e = tid>>2, d = (tid&3)*16 .. +15.
    {
        size_t scb = ((size_t)(bb * H_ + h) * NC_) * (size_t)(D_ * D_);
        int p = tid * 16, e = p >> 6, d0 = p & 63;
        float a[16];
        for (int i = 0; i < 16; i++) a[i] = 0.f;
        for (int j = 0; j < c; j++) {
            const unsigned short* sj = Sct + scb + (size_t)j * (D_ * D_) + p;
            ushortx8 lo = *(const ushortx8*)(sj);
            ushortx8 hi = *(const ushortx8*)(sj + 8);
            for (int i = 0; i < 8; i++) { a[i] += b2f(lo[i]); a[8 + i] += b2f(hi[i]); }
        }
        for (int v4 = 0; v4 < 4; v4++) {
            ushortx4 o;
            for (int i = 0; i < 4; i++) o[i] = f2b(a[v4 * 4 + i]);
            *(ushortx4*)(ovl + e * 68 + d0 + v4 * 4) = o;
        }
    }
    // ---- z_prev (fp32) ----
    if (tid < 64) {
        size_t zb = ((size_t)(bb * H_ + h) * NC_) * D_;
        float zr = 0.f;
        for (int j = 0; j < c; j++) zr += zc[zb + (size_t)j * D_ + tid];
        zsh[tid] = zr;
    }

    // ---- Q fragments: block b rows rb[b]*16+lm, k cols kk*32+lq*8 (global->reg) ----
    short8 aq[2][2];
    for (int b = 0; b < 2; b++)
        for (int kk = 0; kk < 2; kk++)
            aq[b][kk] = *(const short8*)(qkv + (rowb + rb[b] * 16 + lm) * 3072 + qcol + kk * 32 + lq * 8);
    __syncthreads();

    // ---- phase A: acc[b] = Q_b @ S_prev (bs hoisted across blocks) ----
    floatx4 acc[2][4];
    for (int b = 0; b < 2; b++) for (int ni = 0; ni < 4; ni++) acc[b][ni] = floatx4{0.f, 0.f, 0.f, 0.f};
    for (int kk = 0; kk < 2; kk++)
        for (int ni = 0; ni < 4; ni++) {
            short8 bs = *(const short8*)(ovl + (ni * 16 + lm) * 68 + kk * 32 + lq * 8);
            for (int b = 0; b < 2; b++)
                acc[b][ni] = __builtin_amdgcn_mfma_f32_16x16x32_bf16(aq[b][kk], bs, acc[b][ni], 0, 0, 0);
        }
    // ---- dsum init: q . z_prev ----
    float dsum[2][4];
    {
        float4 z4 = *(const float4*)(zsh + lm * 4);
        for (int b = 0; b < 2; b++)
            for (int reg = 0; reg < 4; reg++) {
                int row = rb[b] * 16 + lq * 4 + reg;
                ushortx4 q4 = *(const ushortx4*)(qkv + (rowb + row) * 3072 + qcol + lm * 4);
                dsum[b][reg] = b2f(q4[0]) * z4.x + b2f(q4[1]) * z4.y + b2f(q4[2]) * z4.z + b2f(q4[3]) * z4.w;
            }
    }
    __syncthreads();  // all waves done reading S_prev^T from ovl before P writes

    // ---- balanced intra-chunk loop: per block b, 16-col K-tiles jt = 0..rb[b] ----
    for (int b = 0; b < 2; b++) {
        int R = rb[b];
        int prow = R * 16;                              // this block's P panel rows
        for (int jt = 0; jt <= R; jt++) {
            floatx4 pa = floatx4{0.f, 0.f, 0.f, 0.f};
            for (int kk = 0; kk < 2; kk++) {
                short8 bk = *(const short8*)(ks + (jt * 16 + lm) * 68 + kk * 32 + lq * 8);
                pa = __builtin_amdgcn_mfma_f32_16x16x32_bf16(aq[b][kk], bk, pa, 0, 0, 0);
            }
            bool diag = (jt == R);
            for (int reg = 0; reg < 4; reg++) {
                int il = lq * 4 + reg;                  // row within 16-block
                float v = pa[reg];
                if (diag && lm > il) v = 0.f;           // causal mask on diagonal tile
                dsum[b][reg] += v;
                ovl[(prow + il) * 36 + (jt & 1) * 16 + lm] = f2b(v);
            }
            if ((jt & 1) || jt == R) {
                if (!(jt & 1)) {                        // odd count tail: zero cols 16..31
                    for (int reg = 0; reg < 4; reg++)
                        ovl[(prow + lq * 4 + reg) * 36 + 16 + lm] = 0;
                }
                int pair = jt >> 1;
                short8 ap = *(const short8*)(ovl + (prow + lm) * 36 + lq * 8);
                for (int ni = 0; ni < 4; ni++) {
                    short8 bv = *(const short8*)(vt + (ni * 16 + lm) * 132 + pair * 32 + lq * 8);
                    acc[b][ni] = __builtin_amdgcn_mfma_f32_16x16x32_bf16(ap, bv, acc[b][ni], 0, 0, 0);
                }
            }
        }
    }

    // ---- reduce dsum across the 16-lane col group ----
    for (int off = 1; off < 16; off <<= 1)
        for (int b = 0; b < 2; b++)
            for (int reg = 0; reg < 4; reg++)
                dsum[b][reg] += __shfl_xor(dsum[b][reg], off);

    // ---- epilogue: out = num / den ----
    for (int b = 0; b < 2; b++)
        for (int reg = 0; reg < 4; reg++) {
            float inv = 1.f / (dsum[b][reg] + EPS_);
            int row = rb[b] * 16 + lq * 4 + reg;
            for (int ni = 0; ni < 4; ni++)
                attn[(rowb + row) * E_ + h * D_ + ni * 16 + lm] = f2b(acc[b][ni][reg] * inv);
        }
}

extern "C" void kernel_launch(void* const* d_in, const int* in_sizes, int n_in,
                              void* d_out, int out_size, void* d_ws, size_t ws_size,
                              hipStream_t stream) {
    const float* x  = (const float*)d_in[0];
    const float* Wq = (const float*)d_in[1];
    const float* Wk = (const float*)d_in[2];
    const float* Wv = (const float*)d_in[3];
    const float* Wo = (const float*)d_in[4];
    const float* bo = (const float*)d_in[5];
    float* out = (float*)d_out;

    const size_t MB = 1024 * 1024;
    uint8_t* ws = (uint8_t*)d_ws;
    unsigned short* xb    = (unsigned short*)(ws + 0);        // 8 MB, reused as attn buffer
    unsigned short* wb    = (unsigned short*)(ws + 8 * MB);   // 8 MB (Wq|Wk|Wv|Wo bf16)
    unsigned short* wob   = wb + 3 * E_ * E_;
    unsigned short* qkvb  = (unsigned short*)(ws + 16 * MB);  // 24 MB
    unsigned short* sctb  = (unsigned short*)(ws + 40 * MB);  // 4 MB (bf16 S_c^T)
    float* zc = (float*)(ws + 48 * MB);                       // 128 KB
    unsigned short* attnb = xb;

    convert_all<<<(M_ * E_ + 4 * E_ * E_) / 1024, 256, 0, stream>>>(x, Wq, Wk, Wv, Wo, xb);

    gemm_qkv<<<dim3(16, 16), 512, 0, stream>>>(xb, wb, qkvb);
    chunk_sums<<<dim3(NC_, H_, B_), 256, 0, stream>>>(qkvb, sctb, zc);
    attn_kernel<<<dim3(NC_, H_, B_), 256, 0, stream>>>(qkvb, sctb, zc, attnb);
    gemm_out<<<dim3(16, 32), 256, 0, stream>>>(attnb, wob, bo, out);
}

// Round 14
// 151.734 us; speedup vs baseline: 1.0321x; 1.0321x over previous
//
#include <hip/hip_runtime.h>
#include <hip/hip_bf16.h>
#include <stdint.h>

typedef __attribute__((ext_vector_type(4)))  float  floatx4;
typedef __attribute__((ext_vector_type(8)))  short  short8;
typedef __attribute__((ext_vector_type(8)))  unsigned short ushortx8;
typedef __attribute__((ext_vector_type(4)))  unsigned short ushortx4;

#define B_  2
#define T_  2048
#define E_  1024
#define H_  16
#define D_  64
#define C_  128
#define NC_ 16
#define M_  4096   /* B*T */
#define EPS_ 1e-5f

__device__ __forceinline__ unsigned short f2b(float f) {
    union { float f; unsigned int u; } v; v.f = f;
    unsigned int r = v.u + 0x7fffu + ((v.u >> 16) & 1u);
    return (unsigned short)(r >> 16);
}
__device__ __forceinline__ float b2f(unsigned short b) {
    union { unsigned int u; float f; } v; v.u = ((unsigned int)b) << 16;
    return v.f;
}

// Swizzled fragment staging (R3/R4; R7/R9/R10/R13 errata):
//   staging tile = 16 rows x 32 k (1 KB). lane i fetches global (row = i>>2,
//   kseg = (i&3) ^ ((i>>3)&3)) -> LDS slot i (16B). Fragment read: lane l
//   reads slot sigma(l&15, l>>4) with a WAVE-UNIFORM tile base (R7 errata).
//   R9: sigma-staged GEMM fragments MUST come from LDS. R10: no blockIdx swizzle.
//   R15: tile growth alone is not the lever. R16: dbuf+syncthreads = only -10%.
//   R17: counted vmcnt + raw s_barrier; wall 161.5. R18: separate prefix
//   kernel = net loss. R19: device-scope fences in hot path = disaster.
//   R20: 192-wide @ 4 waves/1 blk/CU = collapse (occupancy). R21: wall
//   accounting non-additive (async fill). R22: qkv 256x192 @ 512thr/8waves/
//   1 blk/CU -> 157.0 (validated). R23: triangle balancing FLAT -> attn is
//   traffic-bound, not MFMA-bound. R24: bf16 pre-transposed chunk states ->
//   153.5 = BEST (validated, absmax unchanged). R25: 4-phase qkv K-step ->
//   156.6 REGRESSION (+3.1): extra per-phase barriers serialize 8 waves at
//   1 blk/CU. Schedule variants at this geometry exhausted.
//   R26 (RESUBMIT — R13 bench was a container failure, no data): pure
//   revert to R24 (best measured, 153.5).
__device__ __forceinline__ int stage_seg(int i) { return (i & 3) ^ ((i >> 3) & 3); }
__device__ __forceinline__ int frag_slot(int lane) {
    int m = lane & 15, q = lane >> 4;
    return m * 4 + (q ^ ((m >> 1) & 3));
}

// ---------------- fused fp32 -> bf16 convert: x | Wq | Wk | Wv | Wo ----------------
__global__ __launch_bounds__(256) void convert_all(const float* __restrict__ x,
                                                   const float* __restrict__ Wq,
                                                   const float* __restrict__ Wk,
                                                   const float* __restrict__ Wv,
                                                   const float* __restrict__ Wo,
                                                   unsigned short* __restrict__ dst) {
    int i = (blockIdx.x * 256 + threadIdx.x) * 4;
    const float* s; int off;
    if (i < M_ * E_) { s = x; off = i; }
    else {
        int j = i - M_ * E_;
        int which = j >> 20;
        s = (which == 0) ? Wq : (which == 1) ? Wk : (which == 2) ? Wv : Wo;
        off = j & ((1 << 20) - 1);
    }
    float4 f = *(const float4*)(s + off);
    ushortx4 o;
    o[0] = f2b(f.x); o[1] = f2b(f.y); o[2] = f2b(f.z); o[3] = f2b(f.w);
    *(ushortx4*)(dst + i) = o;
}

// ---------------- QKV projection GEMM: C[4096,3072] = X @ W^T, phi on q,k ----------------
// R22 (validated): 256x192 tile, BK=64, 512 thr / 8 waves (2x4), dbuf 112 KB,
// grid 16x16 = 256 = 1 blk/CU, counted-vmcnt 2-phase.
__global__ __launch_bounds__(512) void gemm_qkv(const unsigned short* __restrict__ A,
                                                const unsigned short* __restrict__ Bm,
                                                unsigned short* __restrict__ Cb) {
    const int N = 3 * E_, K = E_;
    __shared__ __align__(16) unsigned short smem[57344];   // 112 KB
    unsigned short* at0 = smem;                            // 32 tiles (32 KB)
    unsigned short* bt0 = smem + 16384;                    // 24 tiles (24 KB)
    unsigned short* at1 = smem + 28672;
    unsigned short* bt1 = smem + 45056;
    int tid = threadIdx.x;
    int wave = tid >> 6, lane = tid & 63;
    int wr = wave >> 2, wc = wave & 3;                     // 2 x 4 wave grid
    int m = lane & 15, q = lane >> 4;
    int srow = lane >> 2, sseg = stage_seg(lane);
    int fs = frag_slot(lane);
    int row0 = blockIdx.y * 256, col0 = blockIdx.x * 192;
    floatx4 acc[8][3];
    for (int i = 0; i < 8; i++) for (int j = 0; j < 3; j++) acc[i][j] = floatx4{0.f, 0.f, 0.f, 0.f};

    auto stageA = [&](unsigned short* at, int k0) {      // 4 loads/wave: 32 A tiles
        for (int p = 0; p < 4; p++) {
            int t = p * 8 + wave;                        // rb = t&15, kh = t>>4
            const unsigned short* ga = A + (size_t)(row0 + (t & 15) * 16 + srow) * K + k0 + (t >> 4) * 32 + sseg * 8;
            __builtin_amdgcn_global_load_lds((const __attribute__((address_space(1))) unsigned int*)ga,
                (__attribute__((address_space(3))) unsigned int*)(at + t * 512), 16, 0, 0);
        }
    };
    auto stageB = [&](unsigned short* bt, int k0) {      // 3 loads/wave: 24 B tiles
        for (int p = 0; p < 3; p++) {
            int u = p * 8 + wave;                        // rb = u%12, kh = u/12
            int kh = u / 12, rb = u - kh * 12;
            const unsigned short* gb = Bm + (size_t)(col0 + rb * 16 + srow) * K + k0 + kh * 32 + sseg * 8;
            __builtin_amdgcn_global_load_lds((const __attribute__((address_space(1))) unsigned int*)gb,
                (__attribute__((address_space(3))) unsigned int*)(bt + u * 512), 16, 0, 0);
        }
    };
    short8 af[8], bf[3];
    auto frags = [&](const unsigned short* at, const unsigned short* bt, int kh) {
        for (int mi = 0; mi < 8; mi++) af[mi] = *(const short8*)(at + (kh * 16 + wr * 8 + mi) * 512 + fs * 8);
        for (int ni = 0; ni < 3; ni++) bf[ni] = *(const short8*)(bt + (kh * 12 + wc * 3 + ni) * 512 + fs * 8);
    };
    auto mfma24 = [&]() {
        __builtin_amdgcn_s_setprio(1);
        for (int mi = 0; mi < 8; mi++)
            for (int ni = 0; ni < 3; ni++)
                acc[mi][ni] = __builtin_amdgcn_mfma_f32_16x16x32_bf16(af[mi], bf[ni], acc[mi][ni], 0, 0, 0);
        __builtin_amdgcn_s_setprio(0);
    };

    stageA(at0, 0); stageB(bt0, 0);                      // 7 loads in flight
    for (int k0 = 0; k0 < K; k0 += 128) {
        // ---- step A: compute (at0,bt0) @ k0 ----
        stageA(at1, k0 + 64);                            // outstanding <= 11
        asm volatile("s_waitcnt vmcnt(4)" ::: "memory"); // cur 7 retired; next A in flight
        __builtin_amdgcn_s_barrier();
        frags(at0, bt0, 0);
        mfma24();
        frags(at0, bt0, 1);
        stageB(bt1, k0 + 64);                            // outstanding <= 7
        mfma24();
        __builtin_amdgcn_s_barrier();
        // ---- step B: compute (at1,bt1) @ k0+64 ----
        if (k0 + 128 < K) {
            stageA(at0, k0 + 128);
            asm volatile("s_waitcnt vmcnt(4)" ::: "memory");
        } else {
            asm volatile("s_waitcnt vmcnt(0)" ::: "memory");
        }
        __builtin_amdgcn_s_barrier();
        frags(at1, bt1, 0);
        mfma24();
        frags(at1, bt1, 1);
        if (k0 + 128 < K) stageB(bt0, k0 + 128);
        mfma24();
        __builtin_amdgcn_s_barrier();
    }

    // ---- epilogue: LDS bounce -> coalesced 16B stores ----
    unsigned short* epi = smem + wave * 1792;
    for (int ch = 0; ch < 4; ch++) {
        if (ch) asm volatile("" ::: "memory");
        for (int mi2 = 0; mi2 < 2; mi2++) {
            int mi = ch * 2 + mi2;
            for (int ni = 0; ni < 3; ni++)
                for (int reg = 0; reg < 4; reg++) {
                    int lr = mi2 * 16 + q * 4 + reg;
                    int colw = col0 + wc * 48 + ni * 16 + m;
                    float v = acc[mi][ni][reg];
                    if (colw < 2 * E_) v = (v > 0.f) ? (v + 1.f) : __expf(v);
                    epi[lr * 56 + ni * 16 + m] = f2b(v);
                }
        }
        asm volatile("" ::: "memory");
        for (int slot = 0; slot < 3; slot++) {
            int s = slot * 64 + lane;                    // 192 slots = 32 rows x 6 segs
            int lr = s / 6, seg = s - lr * 6;
            const unsigned short* p = epi + lr * 56 + seg * 8;
            ushortx4 lo = *(const ushortx4*)(p);
            ushortx4 hi = *(const ushortx4*)(p + 4);
            ushortx8 val;
            for (int e = 0; e < 4; e++) { val[e] = lo[e]; val[e + 4] = hi[e]; }
            int row = row0 + wr * 128 + ch * 32 + lr;
            int col = col0 + wc * 48 + seg * 8;
            *(ushortx8*)(Cb + (size_t)row * N + col) = val;
        }
    }
}

// ---------------- Output GEMM: out[4096,1024] = attn @ Wo^T + bo (fp32 out) ----------------
// R17: 128x64 tile, BK=64, dbuf, counted-vmcnt schedule (stage = 4 A + 2 B).
__global__ __launch_bounds__(256) void gemm_out(const unsigned short* __restrict__ A,
                                                const unsigned short* __restrict__ Bm,
                                                const float* __restrict__ bias,
                                                float* __restrict__ Cf) {
    const int N = E_, K = E_;
    __shared__ __align__(16) unsigned short smem[24576];   // 48 KB: 2 x (at 16KB | bt 8KB)
    unsigned short* at0 = smem;
    unsigned short* bt0 = smem + 8192;
    unsigned short* at1 = smem + 12288;
    unsigned short* bt1 = smem + 20480;
    int tid = threadIdx.x;
    int wave = tid >> 6, lane = tid & 63;
    int wr = wave >> 1, wc = wave & 1;
    int m = lane & 15, q = lane >> 4;
    int srow = lane >> 2, sseg = stage_seg(lane);
    int fs = frag_slot(lane);
    int row0 = blockIdx.y * 128, col0 = blockIdx.x * 64;
    floatx4 acc[4][2];
    for (int i = 0; i < 4; i++) for (int j = 0; j < 2; j++) acc[i][j] = floatx4{0.f, 0.f, 0.f, 0.f};

    auto stageA = [&](unsigned short* at, int k0) {
        for (int p = 0; p < 4; p++) {
            int t = p * 4 + wave;
            const unsigned short* ga = A + (size_t)(row0 + (t & 7) * 16 + srow) * K + k0 + (t >> 3) * 32 + sseg * 8;
            __builtin_amdgcn_global_load_lds((const __attribute__((address_space(1))) unsigned int*)ga,
                (__attribute__((address_space(3))) unsigned int*)(at + t * 512), 16, 0, 0);
        }
    };
    auto stageB = [&](unsigned short* bt, int k0) {
        for (int p = 0; p < 2; p++) {
            int u = p * 4 + wave;
            const unsigned short* gb = Bm + (size_t)(col0 + (u & 3) * 16 + srow) * K + k0 + (u >> 2) * 32 + sseg * 8;
            __builtin_amdgcn_global_load_lds((const __attribute__((address_space(1))) unsigned int*)gb,
                (__attribute__((address_space(3))) unsigned int*)(bt + u * 512), 16, 0, 0);
        }
    };
    short8 af[4], bf[2];
    auto frags = [&](const unsigned short* at, const unsigned short* bt, int kh) {
        for (int mi = 0; mi < 4; mi++) af[mi] = *(const short8*)(at + (kh * 8 + wr * 4 + mi) * 512 + fs * 8);
        for (int ci = 0; ci < 2; ci++) bf[ci] = *(const short8*)(bt + (kh * 4 + wc * 2 + ci) * 512 + fs * 8);
    };
    auto mfma8 = [&]() {
        __builtin_amdgcn_s_setprio(1);
        for (int mi = 0; mi < 4; mi++)
            for (int ci = 0; ci < 2; ci++)
                acc[mi][ci] = __builtin_amdgcn_mfma_f32_16x16x32_bf16(af[mi], bf[ci], acc[mi][ci], 0, 0, 0);
        __builtin_amdgcn_s_setprio(0);
    };

    stageA(at0, 0); stageB(bt0, 0);
    for (int k0 = 0; k0 < K; k0 += 128) {
        stageA(at1, k0 + 64);
        asm volatile("s_waitcnt vmcnt(4)" ::: "memory");
        __builtin_amdgcn_s_barrier();
        frags(at0, bt0, 0);
        mfma8();
        frags(at0, bt0, 1);
        stageB(bt1, k0 + 64);
        mfma8();
        __builtin_amdgcn_s_barrier();
        if (k0 + 128 < K) {
            stageA(at0, k0 + 128);
            asm volatile("s_waitcnt vmcnt(4)" ::: "memory");
        } else {
            asm volatile("s_waitcnt vmcnt(0)" ::: "memory");
        }
        __builtin_amdgcn_s_barrier();
        frags(at1, bt1, 0);
        mfma8();
        frags(at1, bt1, 1);
        if (k0 + 128 < K) stageB(bt0, k0 + 128);
        mfma8();
        __builtin_amdgcn_s_barrier();
    }

    int qrow = q * 4;
    for (int ci = 0; ci < 2; ci++) {
        int col = col0 + wc * 32 + ci * 16 + m;
        float bv = bias[col];
        for (int mi = 0; mi < 4; mi++)
            for (int r2 = 0; r2 < 4; r2++) {
                int row = row0 + wr * 64 + mi * 16 + qrow + r2;
                Cf[(size_t)row * N + col] = acc[mi][ci][r2] + bv;
            }
    }
}

// ---------------- per-chunk S_c^T (bf16, [e][d]) and z_c (MFMA) ----------------
// R24: store the chunk state TRANSPOSED in bf16 — exactly the layout attn's
// S_prev panel (ovl, [e][d]) consumes. z_c stays fp32.
__global__ __launch_bounds__(256) void chunk_sums(const unsigned short* __restrict__ qkv,
                                                  unsigned short* __restrict__ Sct,
                                                  float* __restrict__ zc) {
    int c = blockIdx.x, h = blockIdx.y, bb = blockIdx.z;
    __shared__ __align__(16) unsigned short Kt[64 * 132];   // K^T: [d][t], stride 132
    __shared__ __align__(16) unsigned short Vt[80 * 132];   // V^T rows 0..63; row 64 = ones
    int tid = threadIdx.x;
    int lane = tid & 63, w = tid >> 6;
    size_t rowb = (size_t)bb * T_ + (size_t)c * C_;
    int kcol = E_ + h * D_, vcol = 2 * E_ + h * D_;

    {
        int r4 = (tid >> 3) * 4;            // covers 128 rows
        int seg = (tid & 7) * 8;
        ushortx8 kv[4], vv[4];
        for (int t = 0; t < 4; t++) {
            size_t g = (rowb + r4 + t) * 3072;
            kv[t] = *(const ushortx8*)(qkv + g + kcol + seg);
            vv[t] = *(const ushortx8*)(qkv + g + vcol + seg);
        }
        for (int e = 0; e < 8; e++) {
            ushortx4 ka, va;
            for (int t = 0; t < 4; t++) { ka[t] = kv[t][e]; va[t] = vv[t][e]; }
            *(ushortx4*)(Kt + (seg + e) * 132 + r4) = ka;
            *(ushortx4*)(Vt + (seg + e) * 132 + r4) = va;
        }
    }
    if (tid < 128) Vt[64 * 132 + tid] = 0x3f80;  // ones row (bf16 1.0)
    __syncthreads();

    floatx4 acc[5];
    for (int ni = 0; ni < 5; ni++) acc[ni] = floatx4{0.f, 0.f, 0.f, 0.f};
    int lm = lane & 15, lk = (lane >> 4) * 8;
    for (int k0 = 0; k0 < 128; k0 += 32) {
        short8 af = *(const short8*)(Kt + (w * 16 + lm) * 132 + k0 + lk);
        for (int ni = 0; ni < 5; ni++) {
            short8 bf = *(const short8*)(Vt + (ni * 16 + lm) * 132 + k0 + lk);
            acc[ni] = __builtin_amdgcn_mfma_f32_16x16x32_bf16(af, bf, acc[ni], 0, 0, 0);
        }
    }
    // acc[ni][reg] = S[d = r0+reg][e = ni*16+lm]; store transposed bf16:
    // Sct[e*64 + d]. r0 is 4-aligned -> ushortx4 stores.
    size_t base = ((size_t)(bb * H_ + h) * NC_ + c) * (size_t)(D_ * D_);
    int r0 = w * 16 + (lane >> 4) * 4;
    for (int ni = 0; ni < 4; ni++) {
        ushortx4 o;
        for (int reg = 0; reg < 4; reg++) o[reg] = f2b(acc[ni][reg]);
        *(ushortx4*)(Sct + base + (size_t)(ni * 16 + lm) * D_ + r0) = o;
    }
    if (lm == 0) {
        size_t zb = ((size_t)(bb * H_ + h) * NC_ + c) * D_;
        for (int reg = 0; reg < 4; reg++) zc[zb + r0 + reg] = acc[4][reg];
    }
}

// ---------------- per-chunk attention (MFMA) — R23 balanced triangle + R24 bf16 Sct ----------------
// Wave w owns 16-row blocks {w, 7-w}. S_prev summed from bf16 Sct (fp32
// accumulate, vector loads + vector ovl stores). LDS 43.5 KB, 2 barriers.
__global__ __launch_bounds__(256) void attn_kernel(const unsigned short* __restrict__ qkv,
                                                   const unsigned short* __restrict__ Sct,
                                                   const float* __restrict__ zc,
                                                   unsigned short* __restrict__ attn) {
    int c = blockIdx.x, h = blockIdx.y, bb = blockIdx.z;
    __shared__ __align__(16) unsigned short ks[128 * 68];   // K row-major, stride 68
    __shared__ __align__(16) unsigned short vt[64 * 132];   // V^T
    __shared__ __align__(16) unsigned short ovl[128 * 36];  // S_prev^T (stride 68) then P panel (stride 36)
    __shared__ float zsh[64];
    int tid = threadIdx.x;
    int lane = tid & 63, w = tid >> 6;
    int lm = lane & 15, lq = lane >> 4;
    size_t rowb = (size_t)bb * T_ + (size_t)c * C_;
    int qcol = h * D_, kcol = E_ + h * D_, vcol = 2 * E_ + h * D_;
    int rb[2] = { w, 7 - w };                               // this wave's 16-row blocks

    // ---- stage k row-major (vector writes) ----
    for (int s = 0; s < 4; s++) {
        int off = s * 256 + tid;
        int r = off >> 3, seg = (off & 7) * 8;
        ushortx8 k8 = *(const ushortx8*)(qkv + (rowb + r) * 3072 + kcol + seg);
        *(ushortx8*)(ks + r * 68 + seg) = k8;
    }
    // ---- stage v transposed: 4 rows/thread, b64 column writes ----
    {
        int r4 = (tid >> 3) * 4;
        int seg = (tid & 7) * 8;
        ushortx8 vv[4];
        for (int t = 0; t < 4; t++)
            vv[t] = *(const ushortx8*)(qkv + (rowb + r4 + t) * 3072 + vcol + seg);
        for (int e = 0; e < 8; e++) {
            ushortx4 va;
            for (int t = 0; t < 4; t++) va[t] = vv[t][e];
            *(ushortx4*)(vt + (seg + e) * 132 + r4) = va;
        }
    }
    // ---- S_prev = sum_{j<c} Sct[j] (bf16 terms, fp32 accumulate) ----
    // Sct is already [e][d]: thread owns e = tid>>2, d = (tid&3)*16 .. +15.
    {
        size_t scb = ((size_t)(bb * H_ + h) * NC_) * (size_t)(D_ * D_);
        int p = tid * 16, e = p >> 6, d0 = p & 63;
        float a[16];
        for (int i = 0; i < 16; i++) a[i] = 0.f;
        for (int j = 0; j < c; j++) {
            const unsigned short* sj = Sct + scb + (size_t)j * (D_ * D_) + p;
            ushortx8 lo = *(const ushortx8*)(sj);
            ushortx8 hi = *(const ushortx8*)(sj + 8);
            for (int i = 0; i < 8; i++) { a[i] += b2f(lo[i]); a[8 + i] += b2f(hi[i]); }
        }
        for (int v4 = 0; v4 < 4; v4++) {
            ushortx4 o;
            for (int i = 0; i < 4; i++) o[i] = f2b(a[v4 * 4 + i]);
            *(ushortx4*)(ovl + e * 68 + d0 + v4 * 4) = o;
        }
    }
    // ---- z_prev (fp32) ----
    if (tid < 64) {
        size_t zb = ((size_t)(bb * H_ + h) * NC_) * D_;
        float zr = 0.f;
        for (int j = 0; j < c; j++) zr += zc[zb + (size_t)j * D_ + tid];
        zsh[tid] = zr;
    }

    // ---- Q fragments: block b rows rb[b]*16+lm, k cols kk*32+lq*8 (global->reg) ----
    short8 aq[2][2];
    for (int b = 0; b < 2; b++)
        for (int kk = 0; kk < 2; kk++)
            aq[b][kk] = *(const short8*)(qkv + (rowb + rb[b] * 16 + lm) * 3072 + qcol + kk * 32 + lq * 8);
    __syncthreads();

    // ---- phase A: acc[b] = Q_b @ S_prev (bs hoisted across blocks) ----
    floatx4 acc[2][4];
    for (int b = 0; b < 2; b++) for (int ni = 0; ni < 4; ni++) acc[b][ni] = floatx4{0.f, 0.f, 0.f, 0.f};
    for (int kk = 0; kk < 2; kk++)
        for (int ni = 0; ni < 4; ni++) {
            short8 bs = *(const short8*)(ovl + (ni * 16 + lm) * 68 + kk * 32 + lq * 8);
            for (int b = 0; b < 2; b++)
                acc[b][ni] = __builtin_amdgcn_mfma_f32_16x16x32_bf16(aq[b][kk], bs, acc[b][ni], 0, 0, 0);
        }
    // ---- dsum init: q . z_prev ----
    float dsum[2][4];
    {
        float4 z4 = *(const float4*)(zsh + lm * 4);
        for (int b = 0; b < 2; b++)
            for (int reg = 0; reg < 4; reg++) {
                int row = rb[b] * 16 + lq * 4 + reg;
                ushortx4 q4 = *(const ushortx4*)(qkv + (rowb + row) * 3072 + qcol + lm * 4);
                dsum[b][reg] = b2f(q4[0]) * z4.x + b2f(q4[1]) * z4.y + b2f(q4[2]) * z4.z + b2f(q4[3]) * z4.w;
            }
    }
    __syncthreads();  // all waves done reading S_prev^T from ovl before P writes

    // ---- balanced intra-chunk loop: per block b, 16-col K-tiles jt = 0..rb[b] ----
    for (int b = 0; b < 2; b++) {
        int R = rb[b];
        int prow = R * 16;                              // this block's P panel rows
        for (int jt = 0; jt <= R; jt++) {
            floatx4 pa = floatx4{0.f, 0.f, 0.f, 0.f};
            for (int kk = 0; kk < 2; kk++) {
                short8 bk = *(const short8*)(ks + (jt * 16 + lm) * 68 + kk * 32 + lq * 8);
                pa = __builtin_amdgcn_mfma_f32_16x16x32_bf16(aq[b][kk], bk, pa, 0, 0, 0);
            }
            bool diag = (jt == R);
            for (int reg = 0; reg < 4; reg++) {
                int il = lq * 4 + reg;                  // row within 16-block
                float v = pa[reg];
                if (diag && lm > il) v = 0.f;           // causal mask on diagonal tile
                dsum[b][reg] += v;
                ovl[(prow + il) * 36 + (jt & 1) * 16 + lm] = f2b(v);
            }
            if ((jt & 1) || jt == R) {
                if (!(jt & 1)) {                        // odd count tail: zero cols 16..31
                    for (int reg = 0; reg < 4; reg++)
                        ovl[(prow + lq * 4 + reg) * 36 + 16 + lm] = 0;
                }
                int pair = jt >> 1;
                short8 ap = *(const short8*)(ovl + (prow + lm) * 36 + lq * 8);
                for (int ni = 0; ni < 4; ni++) {
                    short8 bv = *(const short8*)(vt + (ni * 16 + lm) * 132 + pair * 32 + lq * 8);
                    acc[b][ni] = __builtin_amdgcn_mfma_f32_16x16x32_bf16(ap, bv, acc[b][ni], 0, 0, 0);
                }
            }
        }
    }

    // ---- reduce dsum across the 16-lane col group ----
    for (int off = 1; off < 16; off <<= 1)
        for (int b = 0; b < 2; b++)
            for (int reg = 0; reg < 4; reg++)
                dsum[b][reg] += __shfl_xor(dsum[b][reg], off);

    // ---- epilogue: out = num / den ----
    for (int b = 0; b < 2; b++)
        for (int reg = 0; reg < 4; reg++) {
            float inv = 1.f / (dsum[b][reg] + EPS_);
            int row = rb[b] * 16 + lq * 4 + reg;
            for (int ni = 0; ni < 4; ni++)
                attn[(rowb + row) * E_ + h * D_ + ni * 16 + lm] = f2b(acc[b][ni][reg] * inv);
        }
}

extern "C" void kernel_launch(void* const* d_in, const int* in_sizes, int n_in,
                              void* d_out, int out_size, void* d_ws, size_t ws_size,
                              hipStream_t stream) {
    const float* x  = (const float*)d_in[0];
    const float* Wq = (const float*)d_in[1];
    const float* Wk = (const float*)d_in[2];
    const float* Wv = (const float*)d_in[3];
    const float* Wo = (const float*)d_in[4];
    const float* bo = (const float*)d_in[5];
    float* out = (float*)d_out;

    const size_t MB = 1024 * 1024;
    uint8_t* ws = (uint8_t*)d_ws;
    unsigned short* xb    = (unsigned short*)(ws + 0);        // 8 MB, reused as attn buffer
    unsigned short* wb    = (unsigned short*)(ws + 8 * MB);   // 8 MB (Wq|Wk|Wv|Wo bf16)
    unsigned short* wob   = wb + 3 * E_ * E_;
    unsigned short* qkvb  = (unsigned short*)(ws + 16 * MB);  // 24 MB
    unsigned short* sctb  = (unsigned short*)(ws + 40 * MB);  // 4 MB (bf16 S_c^T)
    float* zc = (float*)(ws + 48 * MB);                       // 128 KB
    unsigned short* attnb = xb;

    convert_all<<<(M_ * E_ + 4 * E_ * E_) / 1024, 256, 0, stream>>>(x, Wq, Wk, Wv, Wo, xb);

    gemm_qkv<<<dim3(16, 16), 512, 0, stream>>>(xb, wb, qkvb);
    chunk_sums<<<dim3(NC_, H_, B_), 256, 0, stream>>>(qkvb, sctb, zc);
    attn_kernel<<<dim3(NC_, H_, B_), 256, 0, stream>>>(qkvb, sctb, zc, attnb);
    gemm_out<<<dim3(16, 32), 256, 0, stream>>>(attnb, wob, bo, out);
}